// Round 1
// baseline (913.659 us; speedup 1.0000x reference)
//
#include <hip/hip_runtime.h>

#define Bq 4
#define Sq 2048
#define Dq 512
#define Hq 8
#define DHq 64

typedef __attribute__((ext_vector_type(8))) short bf16x8;
typedef __attribute__((ext_vector_type(4))) float floatx4;

__device__ __forceinline__ unsigned short f2bf(float f) {
  union { float f; unsigned u; } v; v.f = f;
  return (unsigned short)((v.u + 0x7fffu + ((v.u >> 16) & 1u)) >> 16);
}

// async global->LDS, 16B per lane. LDS dest must be linear in lane order.
__device__ __forceinline__ void gload16(const unsigned short* g,
                                        unsigned short* l) {
  __builtin_amdgcn_global_load_lds(
      (const __attribute__((address_space(1))) void*)g,
      (__attribute__((address_space(3))) void*)l, 16, 0, 0);
}

// ---------------------------------------------------------------------------
// Weight transpose + bf16 convert: WT[w][n][k] = bf16(W[k][n]), 4 weights.
// Grid (64, 4): 8x8 tiles of 64x64 per weight.
// ---------------------------------------------------------------------------
__global__ __launch_bounds__(256) void wtrans(
    const float* wq, const float* wk, const float* wv, const float* wo,
    unsigned short* WT) {
  const int wz = blockIdx.y;
  const float* W = (wz == 0) ? wq : (wz == 1) ? wk : (wz == 2) ? wv : wo;
  unsigned short* WTz = WT + (size_t)wz * 512 * 512;
  const int k0 = (blockIdx.x >> 3) << 6;
  const int n0 = (blockIdx.x & 7) << 6;
  const int tid = threadIdx.x;
  __shared__ unsigned short T[64][65];
#pragma unroll
  for (int it = 0; it < 16; ++it) {
    int idx = tid + it * 256;          // 0..4095
    int r = idx >> 6, c = idx & 63;    // r = k_local, c = n_local
    T[c][r] = f2bf(W[(size_t)(k0 + r) * 512 + n0 + c]);
  }
  __syncthreads();
#pragma unroll
  for (int it = 0; it < 2; ++it) {
    int e = tid + it * 256;            // 0..511
    int n = e >> 3, koct = e & 7;
    union { unsigned short u[8]; uint4 v; } pk;
#pragma unroll
    for (int j = 0; j < 8; ++j) pk.u[j] = T[n][koct * 8 + j];
    *(uint4*)&WTz[(size_t)(n0 + n) * 512 + k0 + koct * 8] = pk.v;
  }
}

// ---------------------------------------------------------------------------
// GEMM: C[M=8192, N=512] = A[8192,512] @ W[512,512] + bias
// MODE 0: A f32 (q,k,v via bz), outputs bf16 Qb/Kb (bz 0,1) or transposed
//         Vt[b,h,dh,s] (bz 2). B staged via global_load_lds from bf16 WT.
// MODE 1: A bf16 (ctx), output f32 out. Both sides global_load_lds.
// Tile 128x128x32, 4 waves, 16x16x32 MFMA. LDS fragment-contiguous:
//   addr16(row,k) = ((k>>3)*128 + row)*8 + (k&7)
// ---------------------------------------------------------------------------
template <int MODE>
__global__ __launch_bounds__(256) void gemm_kernel(
    const float* A0, const float* A1, const float* A2,
    const unsigned short* Ab, const unsigned short* WT,
    const float* b0, const float* b1, const float* b2,
    unsigned short* O0, unsigned short* O1, unsigned short* VtO,
    float* Fout) {
  const int bz = blockIdx.z;
  const float* A = (bz == 0) ? A0 : (bz == 1) ? A1 : A2;
  const float* bias = (bz == 0) ? b0 : (bz == 1) ? b1 : b2;
  const unsigned short* WTz = WT + (size_t)((MODE == 1) ? 3 : bz) * 262144;

  const int bm = blockIdx.x;   // 0..63
  const int bn = blockIdx.y;   // 0..3
  const int tid = threadIdx.x;
  const int lane = tid & 63;
  const int w = tid >> 6, wm = w >> 1, wn = w & 1;
  const int lg = lane >> 4, lc = lane & 15;

  __shared__ unsigned short As[4096], Bs[4096];

  floatx4 acc[4][4];
#pragma unroll
  for (int mt = 0; mt < 4; ++mt)
#pragma unroll
    for (int nt = 0; nt < 4; ++nt) acc[mt][nt] = (floatx4){0.f, 0.f, 0.f, 0.f};

  for (int kt = 0; kt < 16; ++kt) {
    __syncthreads();
    if (MODE == 0) {
      // stage A: 128x32 f32 -> bf16, 4 float4 per thread
#pragma unroll
      for (int it = 0; it < 4; ++it) {
        int idx = tid + it * 256;
        int m = idx >> 3, k0 = (idx & 7) << 2;
        const float4 va =
            *(const float4*)(A + (size_t)(bm * 128 + m) * 512 + kt * 32 + k0);
        union { unsigned short u[4]; uint2 v; } pk;
        pk.u[0] = f2bf(va.x); pk.u[1] = f2bf(va.y);
        pk.u[2] = f2bf(va.z); pk.u[3] = f2bf(va.w);
        *(uint2*)&As[(((k0 >> 3) * 128 + m) << 3) + (k0 & 7)] = pk.v;
      }
    } else {
#pragma unroll
      for (int it = 0; it < 2; ++it) {
        int c = tid + it * 256;  // c = koct*128 + row
        gload16(Ab + (size_t)(bm * 128 + (c & 127)) * 512 + kt * 32 +
                    (c >> 7) * 8,
                &As[c << 3]);
      }
    }
    // stage B via async DMA from pre-transposed bf16 WT
#pragma unroll
    for (int it = 0; it < 2; ++it) {
      int c = tid + it * 256;    // c = koct*128 + n
      gload16(WTz + (size_t)(bn * 128 + (c & 127)) * 512 + kt * 32 +
                  (c >> 7) * 8,
              &Bs[c << 3]);
    }
    __syncthreads();

    bf16x8 af[4], bfr[4];
#pragma unroll
    for (int mt = 0; mt < 4; ++mt)
      af[mt] = *(const bf16x8*)&As[(lg * 128 + wm * 64 + mt * 16 + lc) << 3];
#pragma unroll
    for (int nt = 0; nt < 4; ++nt)
      bfr[nt] = *(const bf16x8*)&Bs[(lg * 128 + wn * 64 + nt * 16 + lc) << 3];
#pragma unroll
    for (int mt = 0; mt < 4; ++mt)
#pragma unroll
      for (int nt = 0; nt < 4; ++nt)
        acc[mt][nt] = __builtin_amdgcn_mfma_f32_16x16x32_bf16(
            af[mt], bfr[nt], acc[mt][nt], 0, 0, 0);
  }

  // epilogue: C row = ...+lg*4+r, col = ...+lc
#pragma unroll
  for (int mt = 0; mt < 4; ++mt) {
#pragma unroll
    for (int nt = 0; nt < 4; ++nt) {
      const int col = bn * 128 + wn * 64 + nt * 16 + lc;
      const float bvv = bias[col];
      const int row0 = bm * 128 + wm * 64 + mt * 16 + lg * 4;
      if (MODE == 1) {
#pragma unroll
        for (int r = 0; r < 4; ++r)
          Fout[(size_t)(row0 + r) * 512 + col] = acc[mt][nt][r] + bvv;
      } else if (bz == 2) {
        // V: write transposed Vt[b,h,dh,s]; 4 consecutive s pack into 8B
        union { unsigned short u[4]; uint2 v; } pk;
#pragma unroll
        for (int r = 0; r < 4; ++r) pk.u[r] = f2bf(acc[mt][nt][r] + bvv);
        const int bb = row0 >> 11, s0 = row0 & 2047;
        const int hh = col >> 6, dh = col & 63;
        *(uint2*)&VtO[((size_t)((bb * 8 + hh) * 64 + dh)) * 2048 + s0] = pk.v;
      } else {
        unsigned short* O = (bz == 0) ? O0 : O1;
#pragma unroll
        for (int r = 0; r < 4; ++r)
          O[(size_t)(row0 + r) * 512 + col] = f2bf(acc[mt][nt][r] + bvv);
      }
    }
  }
}

// ---------------------------------------------------------------------------
// Fused causal attention. One wave = 16 query rows, fully independent: NO
// __syncthreads anywhere. K/V read as MFMA fragments straight from L2
// (K,V per (b,h) = 256KB each: L2-resident; staging would be overhead).
// Swapped QK^T: s = mfma(K_frag, Q_frag) -> C[key][q]: each lane owns ONE
// q-row (qi = q0+lc) and 16 keys -> softmax reduce = 15 in-lane ops +
// 2 shfl_xor (vs 32 shuffles before). attn store: packed float4 per nt
// (4 consecutive keys live in-lane), nontemporal to protect L2.
// P->A-frag transpose via per-wave 2KB LDS (4x ds_write_b64, 2x b128 read).
// Per-wave zero-fill of rows' upper triangle balances work across qt.
// XCD swizzle: 4 (b,h) pairs per XCD -> 2MB K+V working set per L2.
// ---------------------------------------------------------------------------
__global__ __launch_bounds__(256) void attn_kernel(
    const unsigned short* __restrict__ Qb, const unsigned short* __restrict__ Kb,
    const unsigned short* __restrict__ Vt, float* __restrict__ attn,
    unsigned short* __restrict__ ctxb) {
  const int lid = blockIdx.x;          // 0..1023
  const int xcd = lid & 7;
  const int idx = lid >> 3;            // 0..127
  const int bh = xcd * 4 + (idx >> 5); // cluster: each XCD owns 4 (b,h) pairs
  const int qt = idx & 31;
  const int b = bh >> 3, h = bh & 7;

  const int tid = threadIdx.x;
  const int lane = tid & 63, w = tid >> 6;
  const int lg = lane >> 4, lc = lane & 15;
  const int q0 = qt * 64 + w * 16;
  const int qi = q0 + lc;              // this lane's query row

  __shared__ unsigned short Ps[4096];
  unsigned short* Pw = &Ps[w * 1024];  // per-wave region, no barrier needed

  // Q fragments (B-operand): lane holds Q[q0+lc][ks*32+lg*8 .. +8]
  bf16x8 bQ[2];
#pragma unroll
  for (int ks = 0; ks < 2; ++ks)
    bQ[ks] = *(const bf16x8*)&Qb[(size_t)(b * Sq + q0 + lc) * Dq + h * DHq +
                                 (ks * 4 + lg) * 8];

  const unsigned short* kb = &Kb[(size_t)(b * Sq) * Dq + h * DHq];
  float mrun = -1e30f, lrun = 0.f;

  // ---------------- pass 1: row max & denom ----------------
  for (int jt = 0; jt <= qt; ++jt) {
    const unsigned short* kt_ = kb + (size_t)(jt * 64) * Dq;
    floatx4 s[4];
#pragma unroll
    for (int nt = 0; nt < 4; ++nt) s[nt] = (floatx4){0.f, 0.f, 0.f, 0.f};
#pragma unroll
    for (int ks = 0; ks < 2; ++ks)
#pragma unroll
      for (int nt = 0; nt < 4; ++nt) {
        bf16x8 ak = *(const bf16x8*)&kt_[(size_t)(nt * 16 + lc) * Dq +
                                         (ks * 4 + lg) * 8];
        s[nt] = __builtin_amdgcn_mfma_f32_16x16x32_bf16(ak, bQ[ks], s[nt],
                                                        0, 0, 0);
      }
    // lane holds s[key = jt*64 + nt*16 + lg*4 + r][q = qi]
    float sv[4][4];
    float mx = -1e30f;
    const int kjb = jt * 64 + lg * 4;
#pragma unroll
    for (int nt = 0; nt < 4; ++nt)
#pragma unroll
      for (int r = 0; r < 4; ++r) {
        float x = s[nt][r] * 0.125f;
        if (kjb + nt * 16 + r > qi) x = -1e30f;
        sv[nt][r] = x;
        mx = fmaxf(mx, x);
      }
    mx = fmaxf(mx, __shfl_xor(mx, 16));
    mx = fmaxf(mx, __shfl_xor(mx, 32));
    const float mnew = fmaxf(mrun, mx);
    float sum = 0.f;
#pragma unroll
    for (int nt = 0; nt < 4; ++nt)
#pragma unroll
      for (int r = 0; r < 4; ++r) sum += __expf(sv[nt][r] - mnew);
    sum += __shfl_xor(sum, 16);
    sum += __shfl_xor(sum, 32);
    lrun = lrun * __expf(mrun - mnew) + sum;
    mrun = mnew;
  }
  const float rinv = 1.0f / lrun;

  // ---------------- pass 2: write attn, accumulate ctx ----------------
  floatx4 ctxa[4];
#pragma unroll
  for (int nt = 0; nt < 4; ++nt) ctxa[nt] = (floatx4){0.f, 0.f, 0.f, 0.f};
  float* abase = attn + (size_t)(b * Hq + h) * Sq * Sq;
  const unsigned short* vb = &Vt[(size_t)((b * Hq + h) * DHq) * Sq];

  for (int jt = 0; jt <= qt; ++jt) {
    const unsigned short* kt_ = kb + (size_t)(jt * 64) * Dq;
    floatx4 s[4];
#pragma unroll
    for (int nt = 0; nt < 4; ++nt) s[nt] = (floatx4){0.f, 0.f, 0.f, 0.f};
#pragma unroll
    for (int ks = 0; ks < 2; ++ks)
#pragma unroll
      for (int nt = 0; nt < 4; ++nt) {
        bf16x8 ak = *(const bf16x8*)&kt_[(size_t)(nt * 16 + lc) * Dq +
                                         (ks * 4 + lg) * 8];
        s[nt] = __builtin_amdgcn_mfma_f32_16x16x32_bf16(ak, bQ[ks], s[nt],
                                                        0, 0, 0);
      }
    const int kjb = jt * 64 + lg * 4;
#pragma unroll
    for (int nt = 0; nt < 4; ++nt) {
      floatx4 pv;
      union { unsigned short u[4]; uint2 v2; } pb;
#pragma unroll
      for (int r = 0; r < 4; ++r) {
        float x = s[nt][r] * 0.125f;
        float p = (kjb + nt * 16 + r > qi) ? 0.f : __expf(x - mrun) * rinv;
        pv[r] = p;
        pb.u[r] = f2bf(p);
      }
      // 4 consecutive keys of row qi -> one 16B nontemporal store
      __builtin_nontemporal_store(
          pv, (floatx4*)&abase[(size_t)qi * Sq + jt * 64 + nt * 16 + lg * 4]);
      // P into A-frag layout: addr16(m=lc, k=nt*16+lg*4+r)
      *(uint2*)&Pw[((nt * 2 + (lg >> 1)) * 16 + lc) * 8 + (lg & 1) * 4] =
          pb.v2;
    }
    // PV: ctx[q][d] += P[q][key] @ Vt[d][key]
    bf16x8 ap[2];
#pragma unroll
    for (int ks = 0; ks < 2; ++ks)
      ap[ks] = *(const bf16x8*)&Pw[((ks * 4 + lg) * 16 + lc) * 8];
#pragma unroll
    for (int ks = 0; ks < 2; ++ks)
#pragma unroll
      for (int nt = 0; nt < 4; ++nt) {
        bf16x8 bv = *(const bf16x8*)&vb[(size_t)(nt * 16 + lc) * Sq + jt * 64 +
                                        (ks * 4 + lg) * 8];
        ctxa[nt] = __builtin_amdgcn_mfma_f32_16x16x32_bf16(ap[ks], bv,
                                                           ctxa[nt], 0, 0, 0);
      }
  }

  // ctx (bf16, [B,S,D] with head offset): C row = q0+lg*4+r, col = nt*16+lc
#pragma unroll
  for (int nt = 0; nt < 4; ++nt)
#pragma unroll
    for (int r = 0; r < 4; ++r)
      ctxb[(size_t)(b * Sq + q0 + lg * 4 + r) * Dq + h * DHq + nt * 16 + lc] =
          f2bf(ctxa[nt][r]);

  // zero-fill this wave's 16 rows, cols [(qt+1)*64, S). Work ~ (31-qt):
  // balances against the attn work ~ qt.
  const floatx4 z4 = {0.f, 0.f, 0.f, 0.f};
  const int kend = (qt + 1) * 64;
  for (int rr = 0; rr < 16; ++rr) {
    float* rp = abase + (size_t)(q0 + rr) * Sq;
    for (int c = kend + lane * 4; c < Sq; c += 256)
      __builtin_nontemporal_store(z4, (floatx4*)&rp[c]);
  }
}

extern "C" void kernel_launch(void* const* d_in, const int* in_sizes, int n_in,
                              void* d_out, int out_size, void* d_ws,
                              size_t ws_size, hipStream_t stream) {
  const float* q = (const float*)d_in[0];
  const float* k = (const float*)d_in[1];
  const float* v = (const float*)d_in[2];
  // d_in[3] = mask (causal triu, hard-coded in kernel)
  const float* wq = (const float*)d_in[4];
  const float* bq = (const float*)d_in[5];
  const float* wk = (const float*)d_in[6];
  const float* bk = (const float*)d_in[7];
  const float* wv = (const float*)d_in[8];
  const float* bv = (const float*)d_in[9];
  const float* wo = (const float*)d_in[10];
  const float* bo = (const float*)d_in[11];

  float* out = (float*)d_out;
  float* attn = out + (size_t)Bq * Sq * Dq;

  // workspace (35.7 MB total, bf16):
  unsigned short* Qb = (unsigned short*)d_ws;               // 8 MB [B,S,D]
  unsigned short* Kb = Qb + (size_t)Bq * Sq * Dq;           // 8 MB [B,S,D]
  unsigned short* Vt = Kb + (size_t)Bq * Sq * Dq;           // 8 MB [B,H,DH,S]
  unsigned short* ctxb = Vt + (size_t)Bq * Sq * Dq;         // 8 MB [B,S,D]
  unsigned short* WTb = ctxb + (size_t)Bq * Sq * Dq;        // 2 MB [4,512,512]

  dim3 blk(256);
  wtrans<<<dim3(64, 4), blk, 0, stream>>>(wq, wk, wv, wo, WTb);

  gemm_kernel<0><<<dim3(64, 4, 3), blk, 0, stream>>>(
      q, k, v, nullptr, WTb, bq, bk, bv, Qb, Kb, Vt, nullptr);

  attn_kernel<<<dim3(1024, 1, 1), blk, 0, stream>>>(Qb, Kb, Vt, attn, ctxb);

  gemm_kernel<1><<<dim3(64, 4, 1), blk, 0, stream>>>(
      nullptr, nullptr, nullptr, ctxb, WTb, bo, nullptr, nullptr, nullptr,
      nullptr, nullptr, out);
}

// Round 3
// 760.266 us; speedup vs baseline: 1.2018x; 1.2018x over previous
//
#include <hip/hip_runtime.h>

#define Bq 4
#define Sq 2048
#define Dq 512
#define Hq 8
#define DHq 64

typedef __attribute__((ext_vector_type(8))) short bf16x8;
typedef __attribute__((ext_vector_type(4))) float floatx4;

__device__ __forceinline__ unsigned short f2bf(float f) {
  union { float f; unsigned u; } v; v.f = f;
  return (unsigned short)((v.u + 0x7fffu + ((v.u >> 16) & 1u)) >> 16);
}

// async global->LDS, 16B per lane. LDS dest must be linear in lane order.
__device__ __forceinline__ void gload16(const unsigned short* g,
                                        unsigned short* l) {
  __builtin_amdgcn_global_load_lds(
      (const __attribute__((address_space(1))) void*)g,
      (__attribute__((address_space(3))) void*)l, 16, 0, 0);
}

// ---------------------------------------------------------------------------
// Weight transpose + bf16 convert: WT[w][n][k] = bf16(W[k][n]), 4 weights.
// ---------------------------------------------------------------------------
__global__ __launch_bounds__(256) void wtrans(
    const float* wq, const float* wk, const float* wv, const float* wo,
    unsigned short* WT) {
  const int wz = blockIdx.y;
  const float* W = (wz == 0) ? wq : (wz == 1) ? wk : (wz == 2) ? wv : wo;
  unsigned short* WTz = WT + (size_t)wz * 512 * 512;
  const int k0 = (blockIdx.x >> 3) << 6;
  const int n0 = (blockIdx.x & 7) << 6;
  const int tid = threadIdx.x;
  __shared__ unsigned short T[64][65];
#pragma unroll
  for (int it = 0; it < 16; ++it) {
    int idx = tid + it * 256;
    int r = idx >> 6, c = idx & 63;
    T[c][r] = f2bf(W[(size_t)(k0 + r) * 512 + n0 + c]);
  }
  __syncthreads();
#pragma unroll
  for (int it = 0; it < 2; ++it) {
    int e = tid + it * 256;
    int n = e >> 3, koct = e & 7;
    union { unsigned short u[8]; uint4 v; } pk;
#pragma unroll
    for (int j = 0; j < 8; ++j) pk.u[j] = T[n][koct * 8 + j];
    *(uint4*)&WTz[(size_t)(n0 + n) * 512 + k0 + koct * 8] = pk.v;
  }
}

// ---------------------------------------------------------------------------
// GEMM: C[M=8192, N=512] = A[8192,512] @ W[512,512] + bias
// MODE 0: A f32 (q,k,v via bz), outputs bf16 Qb/Kb (bz 0,1) or transposed
//         Vt[b,h,dh,s] (bz 2). B staged via global_load_lds from bf16 WT.
// MODE 1: A bf16 (ctx), output f32 out. Both sides global_load_lds.
// Tile 128x128x32, 4 waves, 16x16x32 MFMA. LDS fragment-contiguous:
//   addr16(row,k) = ((k>>3)*128 + row)*8 + (k&7)
// ---------------------------------------------------------------------------
template <int MODE>
__global__ __launch_bounds__(256) void gemm_kernel(
    const float* A0, const float* A1, const float* A2,
    const unsigned short* Ab, const unsigned short* WT,
    const float* b0, const float* b1, const float* b2,
    unsigned short* O0, unsigned short* O1, unsigned short* VtO,
    float* Fout) {
  const int bz = blockIdx.z;
  const float* A = (bz == 0) ? A0 : (bz == 1) ? A1 : A2;
  const float* bias = (bz == 0) ? b0 : (bz == 1) ? b1 : b2;
  const unsigned short* WTz = WT + (size_t)((MODE == 1) ? 3 : bz) * 262144;

  const int bm = blockIdx.x;
  const int bn = blockIdx.y;
  const int tid = threadIdx.x;
  const int lane = tid & 63;
  const int w = tid >> 6, wm = w >> 1, wn = w & 1;
  const int lg = lane >> 4, lc = lane & 15;

  __shared__ unsigned short As[4096], Bs[4096];

  floatx4 acc[4][4];
#pragma unroll
  for (int mt = 0; mt < 4; ++mt)
#pragma unroll
    for (int nt = 0; nt < 4; ++nt) acc[mt][nt] = (floatx4){0.f, 0.f, 0.f, 0.f};

  for (int kt = 0; kt < 16; ++kt) {
    __syncthreads();
    if (MODE == 0) {
#pragma unroll
      for (int it = 0; it < 4; ++it) {
        int idx = tid + it * 256;
        int m = idx >> 3, k0 = (idx & 7) << 2;
        const float4 va =
            *(const float4*)(A + (size_t)(bm * 128 + m) * 512 + kt * 32 + k0);
        union { unsigned short u[4]; uint2 v; } pk;
        pk.u[0] = f2bf(va.x); pk.u[1] = f2bf(va.y);
        pk.u[2] = f2bf(va.z); pk.u[3] = f2bf(va.w);
        *(uint2*)&As[(((k0 >> 3) * 128 + m) << 3) + (k0 & 7)] = pk.v;
      }
    } else {
#pragma unroll
      for (int it = 0; it < 2; ++it) {
        int c = tid + it * 256;
        gload16(Ab + (size_t)(bm * 128 + (c & 127)) * 512 + kt * 32 +
                    (c >> 7) * 8,
                &As[c << 3]);
      }
    }
#pragma unroll
    for (int it = 0; it < 2; ++it) {
      int c = tid + it * 256;
      gload16(WTz + (size_t)(bn * 128 + (c & 127)) * 512 + kt * 32 +
                  (c >> 7) * 8,
              &Bs[c << 3]);
    }
    __syncthreads();

    bf16x8 af[4], bfr[4];
#pragma unroll
    for (int mt = 0; mt < 4; ++mt)
      af[mt] = *(const bf16x8*)&As[(lg * 128 + wm * 64 + mt * 16 + lc) << 3];
#pragma unroll
    for (int nt = 0; nt < 4; ++nt)
      bfr[nt] = *(const bf16x8*)&Bs[(lg * 128 + wn * 64 + nt * 16 + lc) << 3];
#pragma unroll
    for (int mt = 0; mt < 4; ++mt)
#pragma unroll
      for (int nt = 0; nt < 4; ++nt)
        acc[mt][nt] = __builtin_amdgcn_mfma_f32_16x16x32_bf16(
            af[mt], bfr[nt], acc[mt][nt], 0, 0, 0);
  }

#pragma unroll
  for (int mt = 0; mt < 4; ++mt) {
#pragma unroll
    for (int nt = 0; nt < 4; ++nt) {
      const int col = bn * 128 + wn * 64 + nt * 16 + lc;
      const float bvv = bias[col];
      const int row0 = bm * 128 + wm * 64 + mt * 16 + lg * 4;
      if (MODE == 1) {
#pragma unroll
        for (int r = 0; r < 4; ++r)
          Fout[(size_t)(row0 + r) * 512 + col] = acc[mt][nt][r] + bvv;
      } else if (bz == 2) {
        union { unsigned short u[4]; uint2 v; } pk;
#pragma unroll
        for (int r = 0; r < 4; ++r) pk.u[r] = f2bf(acc[mt][nt][r] + bvv);
        const int bb = row0 >> 11, s0 = row0 & 2047;
        const int hh = col >> 6, dh = col & 63;
        *(uint2*)&VtO[((size_t)((bb * 8 + hh) * 64 + dh)) * 2048 + s0] = pk.v;
      } else {
        unsigned short* O = (bz == 0) ? O0 : O1;
#pragma unroll
        for (int r = 0; r < 4; ++r)
          O[(size_t)(row0 + r) * 512 + col] = f2bf(acc[mt][nt][r] + bvv);
      }
    }
  }
}

// ---------------------------------------------------------------------------
// Fused causal attention.
// 256 threads = 4 waves; wave w owns 16 query rows; swapped QK^T keeps the
// softmax lane-local (2 shfl_xor per tile). K and V tiles are staged in LDS
// via global_load_lds (coalesced 16B/lane, loaded ONCE per block, shared by
// all 4 waves) -- r1's direct fragment loads were 64-line scatter VMEM and
// made the kernel latency-bound (Occ 25%, all pipes <15%).
// Double-buffered, 1 barrier/tile, next tile prefetched before compute.
// Tiles are [row][128B] with XOR swizzle (octet ^ (row&7)): linear LDS dest +
// pre-swizzled global source (gload_lds can't scatter), swizzled ds_read --
// else b128 fragment reads are 16-way bank conflicts (G4/T2, m214 +89%).
// Heavy-first dispatch: qt = 31 - idx, so work ~ qt blocks start first.
// ---------------------------------------------------------------------------
__global__ __launch_bounds__(256) void attn_kernel(
    const unsigned short* __restrict__ Qb, const unsigned short* __restrict__ Kb,
    const unsigned short* __restrict__ Vt, float* __restrict__ attn,
    unsigned short* __restrict__ ctxb) {
  const int lid = blockIdx.x;          // 0..1023
  const int xcd = lid & 7;
  const int idx = lid >> 3;            // 0..127
  const int bh = xcd * 4 + (idx >> 5); // each XCD owns 4 (b,h): 2MB KV in L2
  const int qt = 31 - (idx & 31);      // heavy-first
  const int b = bh >> 3, h = bh & 7;

  const int tid = threadIdx.x;
  const int lane = tid & 63, w = tid >> 6;
  const int lg = lane >> 4, lc = lane & 15;
  const int q0 = qt * 64 + w * 16;
  const int qi = q0 + lc;              // this lane's query row

  __shared__ unsigned short Ksh[2][4096];  // [buf][row*64 + swz-col], 8KB
  __shared__ unsigned short Vsh[2][4096];  // [buf][dh*64 + swz-col]
  __shared__ unsigned short Ps[4096];
  unsigned short* Pw = &Ps[w * 1024];

  const unsigned short* kb = &Kb[(size_t)(b * Sq) * Dq + h * DHq];
  const unsigned short* vb = &Vt[(size_t)((b * Hq + h) * DHq) * Sq];

  // stage macros: c = tid + it*256 covers 512 x 16B = 8KB tile.
  // LDS linear dest (row = c>>3, octet = c&7); source octet pre-swizzled.
#define STAGE_K(jt_, buf_)                                                    \
  {                                                                           \
    _Pragma("unroll") for (int it = 0; it < 2; ++it) {                        \
      int c = tid + it * 256;                                                 \
      int row = c >> 3;                                                       \
      int sc = ((c & 7) ^ (row & 7)) << 3;                                    \
      gload16(kb + (size_t)((jt_) * 64 + row) * Dq + sc, &Ksh[buf_][c << 3]); \
    }                                                                         \
  }
#define STAGE_V(jt_, buf_)                                                    \
  {                                                                           \
    _Pragma("unroll") for (int it = 0; it < 2; ++it) {                        \
      int c = tid + it * 256;                                                 \
      int dh = c >> 3;                                                        \
      int sc = ((c & 7) ^ (dh & 7)) << 3;                                     \
      gload16(vb + (size_t)dh * Sq + (jt_) * 64 + sc, &Vsh[buf_][c << 3]);    \
    }                                                                         \
  }

  // Q fragments (B-operand): lane holds Q[qi][ks*32+lg*8 .. +8]
  bf16x8 bQ[2];
#pragma unroll
  for (int ks = 0; ks < 2; ++ks)
    bQ[ks] = *(const bf16x8*)&Qb[(size_t)(b * Sq + qi) * Dq + h * DHq +
                                 (ks * 4 + lg) * 8];

  float mrun = -1e30f, lrun = 0.f;

  // ---------------- pass 1: row max & denom ----------------
  STAGE_K(0, 0);
  for (int jt = 0; jt <= qt; ++jt) {
    const int cur = jt & 1;
    __syncthreads();                     // drains vmcnt: K[cur] ready
    if (jt < qt) STAGE_K(jt + 1, cur ^ 1);

    floatx4 s[4];
#pragma unroll
    for (int nt = 0; nt < 4; ++nt) s[nt] = (floatx4){0.f, 0.f, 0.f, 0.f};
#pragma unroll
    for (int ks = 0; ks < 2; ++ks)
#pragma unroll
      for (int nt = 0; nt < 4; ++nt) {
        const int rk = nt * 16 + lc;
        bf16x8 ak = *(const bf16x8*)
            &Ksh[cur][(rk << 6) + ((((ks << 2) + lg) ^ (rk & 7)) << 3)];
        s[nt] = __builtin_amdgcn_mfma_f32_16x16x32_bf16(ak, bQ[ks], s[nt],
                                                        0, 0, 0);
      }
    // lane holds s[key = jt*64 + nt*16 + lg*4 + r][q = qi]
    float sv[4][4];
    float mx = -1e30f;
    const int kjb = jt * 64 + lg * 4;
#pragma unroll
    for (int nt = 0; nt < 4; ++nt)
#pragma unroll
      for (int r = 0; r < 4; ++r) {
        float x = s[nt][r] * 0.125f;
        if (kjb + nt * 16 + r > qi) x = -1e30f;
        sv[nt][r] = x;
        mx = fmaxf(mx, x);
      }
    mx = fmaxf(mx, __shfl_xor(mx, 16));
    mx = fmaxf(mx, __shfl_xor(mx, 32));
    const float mnew = fmaxf(mrun, mx);
    float sum = 0.f;
#pragma unroll
    for (int nt = 0; nt < 4; ++nt)
#pragma unroll
      for (int r = 0; r < 4; ++r) sum += __expf(sv[nt][r] - mnew);
    sum += __shfl_xor(sum, 16);
    sum += __shfl_xor(sum, 32);
    lrun = lrun * __expf(mrun - mnew) + sum;
    mrun = mnew;
  }
  const float rinv = 1.0f / lrun;

  // ---------------- pass 2: write attn, accumulate ctx ----------------
  floatx4 ctxa[4];
#pragma unroll
  for (int nt = 0; nt < 4; ++nt) ctxa[nt] = (floatx4){0.f, 0.f, 0.f, 0.f};
  float* abase = attn + (size_t)(b * Hq + h) * Sq * Sq;

  __syncthreads();                       // pass1 reads done before restage
  STAGE_K(0, 0);
  STAGE_V(0, 0);
  for (int jt = 0; jt <= qt; ++jt) {
    const int cur = jt & 1;
    __syncthreads();                     // K/V[cur] ready
    if (jt < qt) { STAGE_K(jt + 1, cur ^ 1); STAGE_V(jt + 1, cur ^ 1); }

    floatx4 s[4];
#pragma unroll
    for (int nt = 0; nt < 4; ++nt) s[nt] = (floatx4){0.f, 0.f, 0.f, 0.f};
#pragma unroll
    for (int ks = 0; ks < 2; ++ks)
#pragma unroll
      for (int nt = 0; nt < 4; ++nt) {
        const int rk = nt * 16 + lc;
        bf16x8 ak = *(const bf16x8*)
            &Ksh[cur][(rk << 6) + ((((ks << 2) + lg) ^ (rk & 7)) << 3)];
        s[nt] = __builtin_amdgcn_mfma_f32_16x16x32_bf16(ak, bQ[ks], s[nt],
                                                        0, 0, 0);
      }
    const int kjb = jt * 64 + lg * 4;
#pragma unroll
    for (int nt = 0; nt < 4; ++nt) {
      floatx4 pv;
      union { unsigned short u[4]; uint2 v2; } pb;
#pragma unroll
      for (int r = 0; r < 4; ++r) {
        float x = s[nt][r] * 0.125f;
        float p = (kjb + nt * 16 + r > qi) ? 0.f : __expf(x - mrun) * rinv;
        pv[r] = p;
        pb.u[r] = f2bf(p);
      }
      __builtin_nontemporal_store(
          pv, (floatx4*)&abase[(size_t)qi * Sq + jt * 64 + nt * 16 + lg * 4]);
      // P into A-frag layout: addr16(m=lc, k=nt*16+lg*4+r)
      *(uint2*)&Pw[((nt * 2 + (lg >> 1)) * 16 + lc) * 8 + (lg & 1) * 4] =
          pb.v2;
    }
    // PV: ctx[q][dh] += P[q][key] @ Vt[dh][key]
    bf16x8 ap[2];
#pragma unroll
    for (int ks = 0; ks < 2; ++ks)
      ap[ks] = *(const bf16x8*)&Pw[((ks * 4 + lg) * 16 + lc) * 8];
#pragma unroll
    for (int ks = 0; ks < 2; ++ks)
#pragma unroll
      for (int nt = 0; nt < 4; ++nt) {
        const int rv = nt * 16 + lc;
        bf16x8 bv = *(const bf16x8*)
            &Vsh[cur][(rv << 6) + ((((ks << 2) + lg) ^ (rv & 7)) << 3)];
        ctxa[nt] = __builtin_amdgcn_mfma_f32_16x16x32_bf16(ap[ks], bv,
                                                           ctxa[nt], 0, 0, 0);
      }
  }

  // ctx (bf16): C row = q0+lg*4+r, col = nt*16+lc
#pragma unroll
  for (int nt = 0; nt < 4; ++nt)
#pragma unroll
    for (int r = 0; r < 4; ++r)
      ctxb[(size_t)(b * Sq + q0 + lg * 4 + r) * Dq + h * DHq + nt * 16 + lc] =
          f2bf(ctxa[nt][r]);

  // zero-fill this wave's 16 rows, cols [(qt+1)*64, S)
  const floatx4 z4 = {0.f, 0.f, 0.f, 0.f};
  const int kend = (qt + 1) * 64;
  for (int rr = 0; rr < 16; ++rr) {
    float* rp = abase + (size_t)(q0 + rr) * Sq;
    for (int c = kend + lane * 4; c < Sq; c += 256)
      __builtin_nontemporal_store(z4, (floatx4*)&rp[c]);
  }
#undef STAGE_K
#undef STAGE_V
}

extern "C" void kernel_launch(void* const* d_in, const int* in_sizes, int n_in,
                              void* d_out, int out_size, void* d_ws,
                              size_t ws_size, hipStream_t stream) {
  const float* q = (const float*)d_in[0];
  const float* k = (const float*)d_in[1];
  const float* v = (const float*)d_in[2];
  // d_in[3] = mask (causal triu, hard-coded in kernel)
  const float* wq = (const float*)d_in[4];
  const float* bq = (const float*)d_in[5];
  const float* wk = (const float*)d_in[6];
  const float* bk = (const float*)d_in[7];
  const float* wv = (const float*)d_in[8];
  const float* bv = (const float*)d_in[9];
  const float* wo = (const float*)d_in[10];
  const float* bo = (const float*)d_in[11];

  float* out = (float*)d_out;
  float* attn = out + (size_t)Bq * Sq * Dq;

  unsigned short* Qb = (unsigned short*)d_ws;               // 8 MB [B,S,D]
  unsigned short* Kb = Qb + (size_t)Bq * Sq * Dq;           // 8 MB [B,S,D]
  unsigned short* Vt = Kb + (size_t)Bq * Sq * Dq;           // 8 MB [B,H,DH,S]
  unsigned short* ctxb = Vt + (size_t)Bq * Sq * Dq;         // 8 MB [B,S,D]
  unsigned short* WTb = ctxb + (size_t)Bq * Sq * Dq;        // 2 MB [4,512,512]

  dim3 blk(256);
  wtrans<<<dim3(64, 4), blk, 0, stream>>>(wq, wk, wv, wo, WTb);

  gemm_kernel<0><<<dim3(64, 4, 3), blk, 0, stream>>>(
      q, k, v, nullptr, WTb, bq, bk, bv, Qb, Kb, Vt, nullptr);

  attn_kernel<<<dim3(1024, 1, 1), blk, 0, stream>>>(Qb, Kb, Vt, attn, ctxb);

  gemm_kernel<1><<<dim3(64, 4, 1), blk, 0, stream>>>(
      nullptr, nullptr, nullptr, ctxb, WTb, bo, nullptr, nullptr, nullptr,
      nullptr, nullptr, out);
}